// Round 7
// baseline (143.072 us; speedup 1.0000x reference)
//
#include <hip/hip_runtime.h>
#include <math.h>
#include <stdint.h>

#define NB 16384
#define NG 10000          // == 625 g-tiles of 16, exact
#define NTILE 625
#define NCH 10            // g-chunks (grid.y); chunk c covers tiles [625c/10, 625(c+1)/10)
#define WB 2              // b-tiles per wave

typedef _Float16 half8 __attribute__((ext_vector_type(8)));
typedef float    floatx4 __attribute__((ext_vector_type(4)));

// ---------------- Kernel 1: pack per-g K-vector: [Y4_0..8, vx, vy, vz, 0 x20] as f16 ----------------
__global__ __launch_bounds__(256) void k_pack(const float* __restrict__ gv,
                                              half8* __restrict__ y4p) {
    int g = blockIdx.x * 256 + threadIdx.x;
    if (g >= NG) return;
    float x = gv[3 * g + 0], y = gv[3 * g + 1], z = gv[3 * g + 2];
    float n = sqrtf(x * x + y * y + z * z);
    float dn = fmaxf(n, 1e-12f);
    float vx = x / dn, vy = y / dn, vz = z / dn;
    float x2 = vx * vx, y2 = vy * vy, z2 = vz * vz;
    const float c_m4 = (float)(0.75 * sqrt(35.0 / M_PI));
    const float c_m3 = (float)(0.75 * sqrt(35.0 / (2.0 * M_PI)));
    const float c_m2 = (float)(0.75 * sqrt(5.0 / M_PI));
    const float c_m1 = (float)(0.75 * sqrt(5.0 / (2.0 * M_PI)));
    const float c_0  = (float)((3.0 / 16.0) * sqrt(1.0 / M_PI));
    const float c_p2 = (float)((3.0 / 8.0) * sqrt(5.0 / M_PI));
    const float c_p4 = (float)((3.0 / 16.0) * sqrt(35.0 / M_PI));
    half8 h0, h1;
    h0[0] = (_Float16)(c_m4 * vx * vy * (x2 - y2));
    h0[1] = (_Float16)(c_m3 * vy * vz * (3.0f * x2 - y2));
    h0[2] = (_Float16)(c_m2 * vx * vy * (7.0f * z2 - 1.0f));
    h0[3] = (_Float16)(c_m1 * vy * vz * (7.0f * z2 - 3.0f));
    h0[4] = (_Float16)(c_0  * (35.0f * z2 * z2 - 30.0f * z2 + 3.0f));
    h0[5] = (_Float16)(c_m1 * vx * vz * (7.0f * z2 - 3.0f));
    h0[6] = (_Float16)(c_p2 * (x2 - y2) * (7.0f * z2 - 1.0f));
    h0[7] = (_Float16)(c_m3 * vx * vz * (x2 - y2));
    h1 = (half8){0, 0, 0, 0, 0, 0, 0, 0};
    h1[0] = (_Float16)(c_p4 * (x2 * x2 - 6.0f * x2 * y2 + y2 * y2));
    h1[1] = (_Float16)x;   // raw grid vec
    h1[2] = (_Float16)y;
    h1[3] = (_Float16)z;
    const half8 hz = {0, 0, 0, 0, 0, 0, 0, 0};
    half8* dst = y4p + (size_t)g * 4;   // 4 x half8 per g row (K=32)
    dst[0] = h0; dst[1] = h1; dst[2] = hz; dst[3] = hz;
}

// A-fragment for one b: A[m=lane&15][k=quad*8+j]; f4 occupies k=0..8.
__device__ inline half8 make_afrag(const float* __restrict__ f4, int b, int quad) {
    half8 a = {0, 0, 0, 0, 0, 0, 0, 0};
    const float* fr = f4 + (size_t)b * 9;
    if (quad == 0) {
#pragma unroll
        for (int j = 0; j < 8; ++j) a[j] = (_Float16)fr[j];
    } else if (quad == 1) {
        a[0] = (_Float16)fr[8];
    }
    return a;
}

// ---------------- Kernel 2: pass-1 argmax via MFMA, 2 b-tiles per wave, prefetched ----------------
__global__ __launch_bounds__(256) void k_pass1(const float* __restrict__ f4,
                                               const half8* __restrict__ y4p,
                                               float* __restrict__ Pv,
                                               int* __restrict__ Pi) {
    const int lane = threadIdx.x & 63;
    const int w = threadIdx.x >> 6;
    const int W = blockIdx.x * 4 + w;       // wave id; covers b-tiles 2W, 2W+1
    const int quad = lane >> 4, m = lane & 15;
    const int chunk = blockIdx.y;

    half8 af[WB];
#pragma unroll
    for (int tt = 0; tt < WB; ++tt) af[tt] = make_afrag(f4, (W * WB + tt) * 16 + m, quad);

    floatx4 bv[WB];
    int bidx[WB][4];
#pragma unroll
    for (int tt = 0; tt < WB; ++tt) {
        bv[tt] = (floatx4){-INFINITY, -INFINITY, -INFINITY, -INFINITY};
#pragma unroll
        for (int r = 0; r < 4; ++r) bidx[tt][r] = 0;
    }
    const int t0 = (NTILE * chunk) / NCH;
    const int t1 = (NTILE * (chunk + 1)) / NCH;
    const int niter = t1 - t0;
    const half8* bp = y4p + (size_t)(t0 * 16 + m) * 4 + quad;
    int gcur = t0 * 16 + m;
    const floatx4 zero4 = {0.f, 0.f, 0.f, 0.f};

    half8 bf = *bp;                          // prologue load
    bp += 64;
#pragma unroll 2
    for (int t = 0; t < niter - 1; ++t) {
        half8 bfn = *bp;                     // prefetch next tile while computing current
        bp += 64;
#pragma unroll
        for (int tt = 0; tt < WB; ++tt) {
            floatx4 c = __builtin_amdgcn_mfma_f32_16x16x32_f16(af[tt], bf, zero4, 0, 0, 0);
#pragma unroll
            for (int r = 0; r < 4; ++r) {
                bool gt = c[r] > bv[tt][r];
                bv[tt][r]   = gt ? c[r] : bv[tt][r];
                bidx[tt][r] = gt ? gcur : bidx[tt][r];
            }
        }
        gcur += 16;
        bf = bfn;
    }
#pragma unroll
    for (int tt = 0; tt < WB; ++tt) {        // epilogue tile
        floatx4 c = __builtin_amdgcn_mfma_f32_16x16x32_f16(af[tt], bf, zero4, 0, 0, 0);
#pragma unroll
        for (int r = 0; r < 4; ++r) {
            bool gt = c[r] > bv[tt][r];
            bv[tt][r]   = gt ? c[r] : bv[tt][r];
            bidx[tt][r] = gt ? gcur : bidx[tt][r];
        }
    }
    // cross-lane argmax across the 16 cols (lanes with same quad), first-max tie-break
#pragma unroll
    for (int tt = 0; tt < WB; ++tt) {
#pragma unroll
        for (int r = 0; r < 4; ++r) {
            float v = bv[tt][r];
            int   ii = bidx[tt][r];
#pragma unroll
            for (int s = 1; s < 16; s <<= 1) {
                float ov = __shfl_xor(v, s);
                int   oi = __shfl_xor(ii, s);
                if (ov > v || (ov == v && oi < ii)) { v = ov; ii = oi; }
            }
            if (m == 0) {
                int b = (W * WB + tt) * 16 + quad * 4 + r;
                Pv[(size_t)chunk * NB + b] = v;
                Pi[(size_t)chunk * NB + b] = ii;
            }
        }
    }
}

// ---------------- Kernel 3: pass-2 masked argmax via dual MFMA; combines pass-1 inline ----------------
__global__ __launch_bounds__(256) void k_pass2(const float* __restrict__ f4,
                                               const half8* __restrict__ y4p,
                                               const float* __restrict__ gv,
                                               const float* __restrict__ P1v,
                                               const int* __restrict__ P1i,
                                               float* __restrict__ P2v,
                                               int* __restrict__ P2i) {
    const int lane = threadIdx.x & 63;
    const int w = threadIdx.x >> 6;
    const int W = blockIdx.x * 4 + w;
    const int quad = lane >> 4, m = lane & 15;
    const int chunk = blockIdx.y;

    half8 af[WB], df[WB];
#pragma unroll
    for (int tt = 0; tt < WB; ++tt) {
        int b = (W * WB + tt) * 16 + m;
        af[tt] = make_afrag(f4, b, quad);
        half8 d = {0, 0, 0, 0, 0, 0, 0, 0};
        if (quad == 1) {                     // z at k=9,10,11 -> quad1 j=1..3
            // combine pass-1 partials for this b (first-max tie-break, ascending chunks)
            float bvv = -INFINITY; int zi = 0;
#pragma unroll
            for (int cc = 0; cc < NCH; ++cc) {
                float v = P1v[(size_t)cc * NB + b];
                int   i = P1i[(size_t)cc * NB + b];
                if (v > bvv || (v == bvv && i < zi)) { bvv = v; zi = i; }
            }
            d[1] = (_Float16)gv[3 * zi + 0];
            d[2] = (_Float16)gv[3 * zi + 1];
            d[3] = (_Float16)gv[3 * zi + 2];
        }
        df[tt] = d;
    }

    floatx4 bv[WB];
    int bidx[WB][4];
#pragma unroll
    for (int tt = 0; tt < WB; ++tt) {
        bv[tt] = (floatx4){-INFINITY, -INFINITY, -INFINITY, -INFINITY};
#pragma unroll
        for (int r = 0; r < 4; ++r) bidx[tt][r] = 0;
    }
    const int t0 = (NTILE * chunk) / NCH;
    const int t1 = (NTILE * (chunk + 1)) / NCH;
    const int niter = t1 - t0;
    const half8* bp = y4p + (size_t)(t0 * 16 + m) * 4 + quad;
    int gcur = t0 * 16 + m;
    const floatx4 zero4 = {0.f, 0.f, 0.f, 0.f};

    half8 bf = *bp;
    bp += 64;
#pragma unroll 2
    for (int t = 0; t < niter - 1; ++t) {
        half8 bfn = *bp;
        bp += 64;
#pragma unroll
        for (int tt = 0; tt < WB; ++tt) {
            floatx4 cs = __builtin_amdgcn_mfma_f32_16x16x32_f16(af[tt], bf, zero4, 0, 0, 0);
            floatx4 cd = __builtin_amdgcn_mfma_f32_16x16x32_f16(df[tt], bf, zero4, 0, 0, 0);
#pragma unroll
            for (int r = 0; r < 4; ++r) {
                bool ok = (fabsf(cd[r]) < 0.2f) && (cs[r] > bv[tt][r]);
                bv[tt][r]   = ok ? cs[r] : bv[tt][r];
                bidx[tt][r] = ok ? gcur  : bidx[tt][r];
            }
        }
        gcur += 16;
        bf = bfn;
    }
#pragma unroll
    for (int tt = 0; tt < WB; ++tt) {
        floatx4 cs = __builtin_amdgcn_mfma_f32_16x16x32_f16(af[tt], bf, zero4, 0, 0, 0);
        floatx4 cd = __builtin_amdgcn_mfma_f32_16x16x32_f16(df[tt], bf, zero4, 0, 0, 0);
#pragma unroll
        for (int r = 0; r < 4; ++r) {
            bool ok = (fabsf(cd[r]) < 0.2f) && (cs[r] > bv[tt][r]);
            bv[tt][r]   = ok ? cs[r] : bv[tt][r];
            bidx[tt][r] = ok ? gcur  : bidx[tt][r];
        }
    }
#pragma unroll
    for (int tt = 0; tt < WB; ++tt) {
#pragma unroll
        for (int r = 0; r < 4; ++r) {
            float v = bv[tt][r];
            int   ii = bidx[tt][r];
#pragma unroll
            for (int s = 1; s < 16; s <<= 1) {
                float ov = __shfl_xor(v, s);
                int   oi = __shfl_xor(ii, s);
                if (ov > v || (ov == v && oi < ii)) { v = ov; ii = oi; }
            }
            if (m == 0) {
                int b = (W * WB + tt) * 16 + quad * 4 + r;
                P2v[(size_t)chunk * NB + b] = v;
                P2i[(size_t)chunk * NB + b] = ii;
            }
        }
    }
}

// ---------------- Kernel 4: finalize — combine both passes, frame, quaternion, boundary map ----------------
__global__ __launch_bounds__(256) void k_final(const float* __restrict__ f0,
                                               const float* __restrict__ gv,
                                               const float* __restrict__ P1v,
                                               const int* __restrict__ P1i,
                                               const float* __restrict__ P2v,
                                               const int* __restrict__ P2i,
                                               float* __restrict__ out) {
    int b = blockIdx.x * 256 + threadIdx.x;
    float bz = -INFINITY; int zi = 0;
#pragma unroll
    for (int cc = 0; cc < NCH; ++cc) {
        float v = P1v[(size_t)cc * NB + b];
        int   i = P1i[(size_t)cc * NB + b];
        if (v > bz || (v == bz && i < zi)) { bz = v; zi = i; }
    }
    float bx = -INFINITY; int xi = 0;
#pragma unroll
    for (int cc = 0; cc < NCH; ++cc) {
        float v = P2v[(size_t)cc * NB + b];
        int   i = P2i[(size_t)cc * NB + b];
        if (v > bx || (v == bx && i < xi)) { bx = v; xi = i; }
    }
    float zr0 = gv[3 * zi], zr1 = gv[3 * zi + 1], zr2 = gv[3 * zi + 2];
    float xr0 = gv[3 * xi], xr1 = gv[3 * xi + 1], xr2 = gv[3 * xi + 2];
    float zn = sqrtf(zr0 * zr0 + zr1 * zr1 + zr2 * zr2);
    float zd = fmaxf(zn, 1e-12f);
    float z0 = zr0 / zd, z1 = zr1 / zd, z2 = zr2 / zd;
    float pr = xr0 * z0 + xr1 * z1 + xr2 * z2;
    float ux = xr0 - pr * z0, uy = xr1 - pr * z1, uz = xr2 - pr * z2;
    float xn = sqrtf(ux * ux + uy * uy + uz * uz);
    float xd = fmaxf(xn, 1e-12f);
    float x0 = ux / xd, x1 = uy / xd, x2 = uz / xd;
    float y0 = z1 * x2 - z2 * x1;
    float y1 = z2 * x0 - z0 * x2;
    float y2 = z0 * x1 - z1 * x0;
    float m00 = x0, m01 = y0, m02 = z0;
    float m10 = x1, m11 = y1, m12 = z1;
    float m20 = x2, m21 = y2, m22 = z2;
    float q0 = sqrtf(fmaxf(1.0f + m00 + m11 + m22, 0.0f));
    float q1 = sqrtf(fmaxf(1.0f + m00 - m11 - m22, 0.0f));
    float q2 = sqrtf(fmaxf(1.0f - m00 + m11 - m22, 0.0f));
    float q3 = sqrtf(fmaxf(1.0f - m00 - m11 + m22, 0.0f));
    int bq = 0; float qb = q0;
    if (q1 > qb) { qb = q1; bq = 1; }
    if (q2 > qb) { qb = q2; bq = 2; }
    if (q3 > qb) { qb = q3; bq = 3; }
    float dd = 2.0f * fmaxf(qb, 0.1f);
    float wq, qx, qy, qz;
    if (bq == 0)      { wq = q0 * q0;  qx = m21 - m12; qy = m02 - m20; qz = m10 - m01; }
    else if (bq == 1) { wq = m21 - m12; qx = q1 * q1;  qy = m10 + m01; qz = m02 + m20; }
    else if (bq == 2) { wq = m02 - m20; qx = m10 + m01; qy = q2 * q2;  qz = m12 + m21; }
    else              { wq = m10 - m01; qx = m20 + m02; qy = m21 + m12; qz = q3 * q3; }
    out[b * 4 + 0] = wq / dd;
    out[b * 4 + 1] = qx / dd;
    out[b * 4 + 2] = qy / dd;
    out[b * 4 + 3] = qz / dd;
    out[4 * NB + b] = f0[b] * (float)(180.0 / M_PI);
}

extern "C" void kernel_launch(void* const* d_in, const int* in_sizes, int n_in,
                              void* d_out, int out_size, void* d_ws, size_t ws_size,
                              hipStream_t stream) {
    const float* f0 = (const float*)d_in[0];   // [16384, 1]
    const float* f4 = (const float*)d_in[2];   // [16384, 9]
    const float* gv = (const float*)d_in[4];   // [10000, 3]
    float* out = (float*)d_out;
    (void)in_sizes; (void)n_in; (void)out_size; (void)ws_size;

    // ws layout (bytes): y4pack f16[NG*32] = 640000 |
    //   P1v f32[NCH*NB] 655360 | P1i 655360 | P2v 655360 | P2i 655360   (~3.26 MB)
    char* W = (char*)d_ws;
    half8* y4p = (half8*)W;
    float* P1v = (float*)(W + 640000);
    int*   P1i = (int*)(W + 640000 + 655360);
    float* P2v = (float*)(W + 640000 + 2 * 655360);
    int*   P2i = (int*)(W + 640000 + 3 * 655360);

    k_pack<<<(NG + 255) / 256, 256, 0, stream>>>(gv, y4p);
    // 1024 b-tiles / (4 waves/block * WB tiles/wave) = 128 blocks in x; 10 chunks in y
    dim3 grid2(128, NCH);    // 1280 blocks = 5 blocks/CU
    k_pass1<<<grid2, 256, 0, stream>>>(f4, y4p, P1v, P1i);
    k_pass2<<<grid2, 256, 0, stream>>>(f4, y4p, gv, P1v, P1i, P2v, P2i);
    k_final<<<NB / 256, 256, 0, stream>>>(f0, gv, P1v, P1i, P2v, P2i, out);
}

// Round 8
// 137.622 us; speedup vs baseline: 1.0396x; 1.0396x over previous
//
#include <hip/hip_runtime.h>
#include <math.h>
#include <stdint.h>

#define NB 16384
#define NG 10000          // == 625 g-tiles of 16, exact
#define NTILE 625
#define NCH 10            // g-chunks (grid.y); chunk c covers tiles [625c/10, 625(c+1)/10)
#define WB 2              // b-tiles per wave

typedef _Float16 half8 __attribute__((ext_vector_type(8)));
typedef float    floatx4 __attribute__((ext_vector_type(4)));

// ---------------- Kernel 1: pack per-g K-vector: [Y4_0..8, vx, vy, vz, 0 x20] as f16 ----------------
__global__ __launch_bounds__(256) void k_pack(const float* __restrict__ gv,
                                              half8* __restrict__ y4p) {
    int g = blockIdx.x * 256 + threadIdx.x;
    if (g >= NG) return;
    float x = gv[3 * g + 0], y = gv[3 * g + 1], z = gv[3 * g + 2];
    float n = sqrtf(x * x + y * y + z * z);
    float dn = fmaxf(n, 1e-12f);
    float vx = x / dn, vy = y / dn, vz = z / dn;
    float x2 = vx * vx, y2 = vy * vy, z2 = vz * vz;
    const float c_m4 = (float)(0.75 * sqrt(35.0 / M_PI));
    const float c_m3 = (float)(0.75 * sqrt(35.0 / (2.0 * M_PI)));
    const float c_m2 = (float)(0.75 * sqrt(5.0 / M_PI));
    const float c_m1 = (float)(0.75 * sqrt(5.0 / (2.0 * M_PI)));
    const float c_0  = (float)((3.0 / 16.0) * sqrt(1.0 / M_PI));
    const float c_p2 = (float)((3.0 / 8.0) * sqrt(5.0 / M_PI));
    const float c_p4 = (float)((3.0 / 16.0) * sqrt(35.0 / M_PI));
    half8 h0, h1;
    h0[0] = (_Float16)(c_m4 * vx * vy * (x2 - y2));
    h0[1] = (_Float16)(c_m3 * vy * vz * (3.0f * x2 - y2));
    h0[2] = (_Float16)(c_m2 * vx * vy * (7.0f * z2 - 1.0f));
    h0[3] = (_Float16)(c_m1 * vy * vz * (7.0f * z2 - 3.0f));
    h0[4] = (_Float16)(c_0  * (35.0f * z2 * z2 - 30.0f * z2 + 3.0f));
    h0[5] = (_Float16)(c_m1 * vx * vz * (7.0f * z2 - 3.0f));
    h0[6] = (_Float16)(c_p2 * (x2 - y2) * (7.0f * z2 - 1.0f));
    h0[7] = (_Float16)(c_m3 * vx * vz * (x2 - y2));
    h1 = (half8){0, 0, 0, 0, 0, 0, 0, 0};
    h1[0] = (_Float16)(c_p4 * (x2 * x2 - 6.0f * x2 * y2 + y2 * y2));
    h1[1] = (_Float16)x;   // raw grid vec
    h1[2] = (_Float16)y;
    h1[3] = (_Float16)z;
    const half8 hz = {0, 0, 0, 0, 0, 0, 0, 0};
    half8* dst = y4p + (size_t)g * 4;   // 4 x half8 per g row (K=32)
    dst[0] = h0; dst[1] = h1; dst[2] = hz; dst[3] = hz;
}

// A-fragment for one b: A[m=lane&15][k=quad*8+j]; f4 occupies k=0..8.
__device__ inline half8 make_afrag(const float* __restrict__ f4, int b, int quad) {
    half8 a = {0, 0, 0, 0, 0, 0, 0, 0};
    const float* fr = f4 + (size_t)b * 9;
    if (quad == 0) {
#pragma unroll
        for (int j = 0; j < 8; ++j) a[j] = (_Float16)fr[j];
    } else if (quad == 1) {
        a[0] = (_Float16)fr[8];
    }
    return a;
}

// ---------------- Kernel 2: pass-1 argmax via MFMA, 2 b-tiles per wave, prefetched ----------------
// __launch_bounds__(256, 2): VGPR budget 256 >> live set, so MFMA C/D + fragments stay in
// plain VGPRs (no accvgpr mov bloat). Default (256) targeted 8 waves/EU -> 64-VGPR budget ->
// AGPR-form MFMA with ~32 extra mov ops/iter (R7: VGPR_Count=32, VALU-busy 3.3x model).
__global__ __launch_bounds__(256, 2) void k_pass1(const float* __restrict__ f4,
                                                  const half8* __restrict__ y4p,
                                                  float* __restrict__ Pv,
                                                  int* __restrict__ Pi) {
    const int lane = threadIdx.x & 63;
    const int w = threadIdx.x >> 6;
    const int W = blockIdx.x * 4 + w;       // wave id; covers b-tiles 2W, 2W+1
    const int quad = lane >> 4, m = lane & 15;
    const int chunk = blockIdx.y;

    half8 af[WB];
#pragma unroll
    for (int tt = 0; tt < WB; ++tt) af[tt] = make_afrag(f4, (W * WB + tt) * 16 + m, quad);

    floatx4 bv[WB];
    int bidx[WB][4];
#pragma unroll
    for (int tt = 0; tt < WB; ++tt) {
        bv[tt] = (floatx4){-INFINITY, -INFINITY, -INFINITY, -INFINITY};
#pragma unroll
        for (int r = 0; r < 4; ++r) bidx[tt][r] = 0;
    }
    const int t0 = (NTILE * chunk) / NCH;
    const int t1 = (NTILE * (chunk + 1)) / NCH;
    const int niter = t1 - t0;
    const half8* bp = y4p + (size_t)(t0 * 16 + m) * 4 + quad;
    int gcur = t0 * 16 + m;
    const floatx4 zero4 = {0.f, 0.f, 0.f, 0.f};

    half8 bf = *bp;                          // prologue load
    bp += 64;
#pragma unroll 2
    for (int t = 0; t < niter - 1; ++t) {
        half8 bfn = *bp;                     // prefetch next tile while computing current
        bp += 64;
#pragma unroll
        for (int tt = 0; tt < WB; ++tt) {
            floatx4 c = __builtin_amdgcn_mfma_f32_16x16x32_f16(af[tt], bf, zero4, 0, 0, 0);
#pragma unroll
            for (int r = 0; r < 4; ++r) {
                bool gt = c[r] > bv[tt][r];
                bv[tt][r]   = gt ? c[r] : bv[tt][r];
                bidx[tt][r] = gt ? gcur : bidx[tt][r];
            }
        }
        gcur += 16;
        bf = bfn;
    }
#pragma unroll
    for (int tt = 0; tt < WB; ++tt) {        // epilogue tile
        floatx4 c = __builtin_amdgcn_mfma_f32_16x16x32_f16(af[tt], bf, zero4, 0, 0, 0);
#pragma unroll
        for (int r = 0; r < 4; ++r) {
            bool gt = c[r] > bv[tt][r];
            bv[tt][r]   = gt ? c[r] : bv[tt][r];
            bidx[tt][r] = gt ? gcur : bidx[tt][r];
        }
    }
    // cross-lane argmax across the 16 cols (lanes with same quad), first-max tie-break
#pragma unroll
    for (int tt = 0; tt < WB; ++tt) {
#pragma unroll
        for (int r = 0; r < 4; ++r) {
            float v = bv[tt][r];
            int   ii = bidx[tt][r];
#pragma unroll
            for (int s = 1; s < 16; s <<= 1) {
                float ov = __shfl_xor(v, s);
                int   oi = __shfl_xor(ii, s);
                if (ov > v || (ov == v && oi < ii)) { v = ov; ii = oi; }
            }
            if (m == 0) {
                int b = (W * WB + tt) * 16 + quad * 4 + r;
                Pv[(size_t)chunk * NB + b] = v;
                Pi[(size_t)chunk * NB + b] = ii;
            }
        }
    }
}

// ---------------- Kernel 3: pass-2 masked argmax via dual MFMA; combines pass-1 inline ----------------
__global__ __launch_bounds__(256, 2) void k_pass2(const float* __restrict__ f4,
                                                  const half8* __restrict__ y4p,
                                                  const float* __restrict__ gv,
                                                  const float* __restrict__ P1v,
                                                  const int* __restrict__ P1i,
                                                  float* __restrict__ P2v,
                                                  int* __restrict__ P2i) {
    const int lane = threadIdx.x & 63;
    const int w = threadIdx.x >> 6;
    const int W = blockIdx.x * 4 + w;
    const int quad = lane >> 4, m = lane & 15;
    const int chunk = blockIdx.y;

    half8 af[WB], df[WB];
#pragma unroll
    for (int tt = 0; tt < WB; ++tt) {
        int b = (W * WB + tt) * 16 + m;
        af[tt] = make_afrag(f4, b, quad);
        half8 d = {0, 0, 0, 0, 0, 0, 0, 0};
        if (quad == 1) {                     // z at k=9,10,11 -> quad1 j=1..3
            // combine pass-1 partials for this b (first-max tie-break, ascending chunks)
            float bvv = -INFINITY; int zi = 0;
#pragma unroll
            for (int cc = 0; cc < NCH; ++cc) {
                float v = P1v[(size_t)cc * NB + b];
                int   i = P1i[(size_t)cc * NB + b];
                if (v > bvv || (v == bvv && i < zi)) { bvv = v; zi = i; }
            }
            d[1] = (_Float16)gv[3 * zi + 0];
            d[2] = (_Float16)gv[3 * zi + 1];
            d[3] = (_Float16)gv[3 * zi + 2];
        }
        df[tt] = d;
    }

    floatx4 bv[WB];
    int bidx[WB][4];
#pragma unroll
    for (int tt = 0; tt < WB; ++tt) {
        bv[tt] = (floatx4){-INFINITY, -INFINITY, -INFINITY, -INFINITY};
#pragma unroll
        for (int r = 0; r < 4; ++r) bidx[tt][r] = 0;
    }
    const int t0 = (NTILE * chunk) / NCH;
    const int t1 = (NTILE * (chunk + 1)) / NCH;
    const int niter = t1 - t0;
    const half8* bp = y4p + (size_t)(t0 * 16 + m) * 4 + quad;
    int gcur = t0 * 16 + m;
    const floatx4 zero4 = {0.f, 0.f, 0.f, 0.f};

    half8 bf = *bp;
    bp += 64;
#pragma unroll 2
    for (int t = 0; t < niter - 1; ++t) {
        half8 bfn = *bp;
        bp += 64;
#pragma unroll
        for (int tt = 0; tt < WB; ++tt) {
            floatx4 cs = __builtin_amdgcn_mfma_f32_16x16x32_f16(af[tt], bf, zero4, 0, 0, 0);
            floatx4 cd = __builtin_amdgcn_mfma_f32_16x16x32_f16(df[tt], bf, zero4, 0, 0, 0);
#pragma unroll
            for (int r = 0; r < 4; ++r) {
                bool ok = (fabsf(cd[r]) < 0.2f) && (cs[r] > bv[tt][r]);
                bv[tt][r]   = ok ? cs[r] : bv[tt][r];
                bidx[tt][r] = ok ? gcur  : bidx[tt][r];
            }
        }
        gcur += 16;
        bf = bfn;
    }
#pragma unroll
    for (int tt = 0; tt < WB; ++tt) {
        floatx4 cs = __builtin_amdgcn_mfma_f32_16x16x32_f16(af[tt], bf, zero4, 0, 0, 0);
        floatx4 cd = __builtin_amdgcn_mfma_f32_16x16x32_f16(df[tt], bf, zero4, 0, 0, 0);
#pragma unroll
        for (int r = 0; r < 4; ++r) {
            bool ok = (fabsf(cd[r]) < 0.2f) && (cs[r] > bv[tt][r]);
            bv[tt][r]   = ok ? cs[r] : bv[tt][r];
            bidx[tt][r] = ok ? gcur  : bidx[tt][r];
        }
    }
#pragma unroll
    for (int tt = 0; tt < WB; ++tt) {
#pragma unroll
        for (int r = 0; r < 4; ++r) {
            float v = bv[tt][r];
            int   ii = bidx[tt][r];
#pragma unroll
            for (int s = 1; s < 16; s <<= 1) {
                float ov = __shfl_xor(v, s);
                int   oi = __shfl_xor(ii, s);
                if (ov > v || (ov == v && oi < ii)) { v = ov; ii = oi; }
            }
            if (m == 0) {
                int b = (W * WB + tt) * 16 + quad * 4 + r;
                P2v[(size_t)chunk * NB + b] = v;
                P2i[(size_t)chunk * NB + b] = ii;
            }
        }
    }
}

// ---------------- Kernel 4: finalize — combine both passes, frame, quaternion, boundary map ----------------
__global__ __launch_bounds__(256) void k_final(const float* __restrict__ f0,
                                               const float* __restrict__ gv,
                                               const float* __restrict__ P1v,
                                               const int* __restrict__ P1i,
                                               const float* __restrict__ P2v,
                                               const int* __restrict__ P2i,
                                               float* __restrict__ out) {
    int b = blockIdx.x * 256 + threadIdx.x;
    float bz = -INFINITY; int zi = 0;
#pragma unroll
    for (int cc = 0; cc < NCH; ++cc) {
        float v = P1v[(size_t)cc * NB + b];
        int   i = P1i[(size_t)cc * NB + b];
        if (v > bz || (v == bz && i < zi)) { bz = v; zi = i; }
    }
    float bx = -INFINITY; int xi = 0;
#pragma unroll
    for (int cc = 0; cc < NCH; ++cc) {
        float v = P2v[(size_t)cc * NB + b];
        int   i = P2i[(size_t)cc * NB + b];
        if (v > bx || (v == bx && i < xi)) { bx = v; xi = i; }
    }
    float zr0 = gv[3 * zi], zr1 = gv[3 * zi + 1], zr2 = gv[3 * zi + 2];
    float xr0 = gv[3 * xi], xr1 = gv[3 * xi + 1], xr2 = gv[3 * xi + 2];
    float zn = sqrtf(zr0 * zr0 + zr1 * zr1 + zr2 * zr2);
    float zd = fmaxf(zn, 1e-12f);
    float z0 = zr0 / zd, z1 = zr1 / zd, z2 = zr2 / zd;
    float pr = xr0 * z0 + xr1 * z1 + xr2 * z2;
    float ux = xr0 - pr * z0, uy = xr1 - pr * z1, uz = xr2 - pr * z2;
    float xn = sqrtf(ux * ux + uy * uy + uz * uz);
    float xd = fmaxf(xn, 1e-12f);
    float x0 = ux / xd, x1 = uy / xd, x2 = uz / xd;
    float y0 = z1 * x2 - z2 * x1;
    float y1 = z2 * x0 - z0 * x2;
    float y2 = z0 * x1 - z1 * x0;
    float m00 = x0, m01 = y0, m02 = z0;
    float m10 = x1, m11 = y1, m12 = z1;
    float m20 = x2, m21 = y2, m22 = z2;
    float q0 = sqrtf(fmaxf(1.0f + m00 + m11 + m22, 0.0f));
    float q1 = sqrtf(fmaxf(1.0f + m00 - m11 - m22, 0.0f));
    float q2 = sqrtf(fmaxf(1.0f - m00 + m11 - m22, 0.0f));
    float q3 = sqrtf(fmaxf(1.0f - m00 - m11 + m22, 0.0f));
    int bq = 0; float qb = q0;
    if (q1 > qb) { qb = q1; bq = 1; }
    if (q2 > qb) { qb = q2; bq = 2; }
    if (q3 > qb) { qb = q3; bq = 3; }
    float dd = 2.0f * fmaxf(qb, 0.1f);
    float wq, qx, qy, qz;
    if (bq == 0)      { wq = q0 * q0;  qx = m21 - m12; qy = m02 - m20; qz = m10 - m01; }
    else if (bq == 1) { wq = m21 - m12; qx = q1 * q1;  qy = m10 + m01; qz = m02 + m20; }
    else if (bq == 2) { wq = m02 - m20; qx = m10 + m01; qy = q2 * q2;  qz = m12 + m21; }
    else              { wq = m10 - m01; qx = m20 + m02; qy = m21 + m12; qz = q3 * q3; }
    out[b * 4 + 0] = wq / dd;
    out[b * 4 + 1] = qx / dd;
    out[b * 4 + 2] = qy / dd;
    out[b * 4 + 3] = qz / dd;
    out[4 * NB + b] = f0[b] * (float)(180.0 / M_PI);
}

extern "C" void kernel_launch(void* const* d_in, const int* in_sizes, int n_in,
                              void* d_out, int out_size, void* d_ws, size_t ws_size,
                              hipStream_t stream) {
    const float* f0 = (const float*)d_in[0];   // [16384, 1]
    const float* f4 = (const float*)d_in[2];   // [16384, 9]
    const float* gv = (const float*)d_in[4];   // [10000, 3]
    float* out = (float*)d_out;
    (void)in_sizes; (void)n_in; (void)out_size; (void)ws_size;

    // ws layout (bytes): y4pack f16[NG*32] = 640000 |
    //   P1v f32[NCH*NB] 655360 | P1i 655360 | P2v 655360 | P2i 655360   (~3.26 MB)
    char* W = (char*)d_ws;
    half8* y4p = (half8*)W;
    float* P1v = (float*)(W + 640000);
    int*   P1i = (int*)(W + 640000 + 655360);
    float* P2v = (float*)(W + 640000 + 2 * 655360);
    int*   P2i = (int*)(W + 640000 + 3 * 655360);

    k_pack<<<(NG + 255) / 256, 256, 0, stream>>>(gv, y4p);
    // 1024 b-tiles / (4 waves/block * WB tiles/wave) = 128 blocks in x; 10 chunks in y
    dim3 grid2(128, NCH);    // 1280 blocks = 5 blocks/CU
    k_pass1<<<grid2, 256, 0, stream>>>(f4, y4p, P1v, P1i);
    k_pass2<<<grid2, 256, 0, stream>>>(f4, y4p, gv, P1v, P1i, P2v, P2i);
    k_final<<<NB / 256, 256, 0, stream>>>(f0, gv, P1v, P1i, P2v, P2i, out);
}

// Round 9
// 137.160 us; speedup vs baseline: 1.0431x; 1.0034x over previous
//
#include <hip/hip_runtime.h>
#include <math.h>
#include <stdint.h>

#define NB 16384
#define NG 10000
#define NGT 313           // ceil(NG/32) g-tiles of 32; tail of last tile NaN-poisoned
#define NGPAD (NGT * 32)  // 10016
#define NCH 8             // g-chunks; chunk c covers tiles [NGT*c/NCH, NGT*(c+1)/NCH)

typedef _Float16 half8 __attribute__((ext_vector_type(8)));
typedef float    floatx16 __attribute__((ext_vector_type(16)));

// ---------------- Kernel 1: pack per-g K=16 row: [Y4_0..8, x, y, z, 0,0,0,0] f16 ----------------
// Rows g in [NG, NGPAD) are all-NaN: any dot with them is NaN, which loses every
// ordered compare -> padded cols can never win either argmax.
__global__ __launch_bounds__(256) void k_pack(const float* __restrict__ gv,
                                              half8* __restrict__ y4p) {
    int g = blockIdx.x * 256 + threadIdx.x;
    if (g >= NGPAD) return;
    half8 h0, h1;
    if (g >= NG) {
        const _Float16 qn = (_Float16)__builtin_nanf("");
#pragma unroll
        for (int i = 0; i < 8; ++i) { h0[i] = qn; h1[i] = qn; }
    } else {
        float x = gv[3 * g + 0], y = gv[3 * g + 1], z = gv[3 * g + 2];
        float n = sqrtf(x * x + y * y + z * z);
        float dn = fmaxf(n, 1e-12f);
        float vx = x / dn, vy = y / dn, vz = z / dn;
        float x2 = vx * vx, y2 = vy * vy, z2 = vz * vz;
        const float c_m4 = (float)(0.75 * sqrt(35.0 / M_PI));
        const float c_m3 = (float)(0.75 * sqrt(35.0 / (2.0 * M_PI)));
        const float c_m2 = (float)(0.75 * sqrt(5.0 / M_PI));
        const float c_m1 = (float)(0.75 * sqrt(5.0 / (2.0 * M_PI)));
        const float c_0  = (float)((3.0 / 16.0) * sqrt(1.0 / M_PI));
        const float c_p2 = (float)((3.0 / 8.0) * sqrt(5.0 / M_PI));
        const float c_p4 = (float)((3.0 / 16.0) * sqrt(35.0 / M_PI));
        h0[0] = (_Float16)(c_m4 * vx * vy * (x2 - y2));
        h0[1] = (_Float16)(c_m3 * vy * vz * (3.0f * x2 - y2));
        h0[2] = (_Float16)(c_m2 * vx * vy * (7.0f * z2 - 1.0f));
        h0[3] = (_Float16)(c_m1 * vy * vz * (7.0f * z2 - 3.0f));
        h0[4] = (_Float16)(c_0  * (35.0f * z2 * z2 - 30.0f * z2 + 3.0f));
        h0[5] = (_Float16)(c_m1 * vx * vz * (7.0f * z2 - 3.0f));
        h0[6] = (_Float16)(c_p2 * (x2 - y2) * (7.0f * z2 - 1.0f));
        h0[7] = (_Float16)(c_m3 * vx * vz * (x2 - y2));
        h1 = (half8){0, 0, 0, 0, 0, 0, 0, 0};
        h1[0] = (_Float16)(c_p4 * (x2 * x2 - 6.0f * x2 * y2 + y2 * y2));  // k=8
        h1[1] = (_Float16)x;   // k=9..11: raw grid vec
        h1[2] = (_Float16)y;
        h1[3] = (_Float16)z;
    }
    half8* dst = y4p + (size_t)g * 2;   // 2 x half8 per g row (K=16, 32 B)
    dst[0] = h0; dst[1] = h1;
}

// A-frag for 32x32x16: lane holds row m=lane&31, k = (lane>>5)*8 + j.
__device__ inline half8 make_afrag32(const float* __restrict__ f4, int b, int kh) {
    half8 a = {0, 0, 0, 0, 0, 0, 0, 0};
    const float* fr = f4 + (size_t)b * 9;
    if (kh == 0) {
#pragma unroll
        for (int j = 0; j < 8; ++j) a[j] = (_Float16)fr[j];
    } else {
        a[0] = (_Float16)fr[8];      // k=8
    }
    return a;
}

// ---------------- Kernel 2: pass-1 argmax via 32x32x16 MFMA, 1 b-tile(32) per wave ----------------
__global__ __launch_bounds__(256, 2) void k_pass1(const float* __restrict__ f4,
                                                  const half8* __restrict__ y4p,
                                                  float* __restrict__ Pv,
                                                  int* __restrict__ Pi) {
    const int lane = threadIdx.x & 63;
    const int w = threadIdx.x >> 6;
    const int W = blockIdx.x * 4 + w;       // b-tile index; b = 32W .. 32W+31
    const int n = lane & 31, kh = lane >> 5;
    const int chunk = blockIdx.y;

    half8 af = make_afrag32(f4, W * 32 + n, kh);

    float bv[16]; int bidx[16];
#pragma unroll
    for (int r = 0; r < 16; ++r) { bv[r] = -INFINITY; bidx[r] = 0; }

    const int t0 = (NGT * chunk) / NCH;
    const int t1 = (NGT * (chunk + 1)) / NCH;
    const half8* bp = y4p + (size_t)(t0 * 32 + n) * 2 + kh;
    int gcur = t0 * 32 + n;                  // this lane's g-column
    const floatx16 zero16 = {0.f,0.f,0.f,0.f, 0.f,0.f,0.f,0.f, 0.f,0.f,0.f,0.f, 0.f,0.f,0.f,0.f};

    half8 bf = *bp;                          // prologue load
    bp += 64;                                // 32 rows * 2 half8
#pragma unroll 2
    for (int t = t0; t < t1 - 1; ++t) {
        half8 bfn = *bp;                     // prefetch next g-tile
        bp += 64;
        floatx16 c = __builtin_amdgcn_mfma_f32_32x32x16_f16(af, bf, zero16, 0, 0, 0);
#pragma unroll
        for (int r = 0; r < 16; ++r) {
            bool gt = c[r] > bv[r];          // NaN (pad) never wins
            bv[r]   = gt ? c[r] : bv[r];
            bidx[r] = gt ? gcur : bidx[r];
        }
        gcur += 32;
        bf = bfn;
    }
    {                                        // epilogue tile
        floatx16 c = __builtin_amdgcn_mfma_f32_32x32x16_f16(af, bf, zero16, 0, 0, 0);
#pragma unroll
        for (int r = 0; r < 16; ++r) {
            bool gt = c[r] > bv[r];
            bv[r]   = gt ? c[r] : bv[r];
            bidx[r] = gt ? gcur : bidx[r];
        }
    }
    // reduce across the 32 g-columns (xor masks stay within each 32-lane half)
#pragma unroll
    for (int r = 0; r < 16; ++r) {
        float v = bv[r];
        int   ii = bidx[r];
#pragma unroll
        for (int s = 1; s < 32; s <<= 1) {
            float ov = __shfl_xor(v, s);
            int   oi = __shfl_xor(ii, s);
            if (ov > v || (ov == v && oi < ii)) { v = ov; ii = oi; }
        }
        if (n == 0) {
            int b = W * 32 + (r & 3) + 8 * (r >> 2) + 4 * kh;   // C/D row mapping
            Pv[(size_t)chunk * NB + b] = v;
            Pi[(size_t)chunk * NB + b] = ii;
        }
    }
}

// ---------------- Kernel 3: pass-2 masked argmax via dual 32x32x16 MFMA ----------------
__global__ __launch_bounds__(256, 2) void k_pass2(const float* __restrict__ f4,
                                                  const half8* __restrict__ y4p,
                                                  const float* __restrict__ gv,
                                                  const float* __restrict__ P1v,
                                                  const int* __restrict__ P1i,
                                                  float* __restrict__ P2v,
                                                  int* __restrict__ P2i) {
    const int lane = threadIdx.x & 63;
    const int w = threadIdx.x >> 6;
    const int W = blockIdx.x * 4 + w;
    const int n = lane & 31, kh = lane >> 5;
    const int chunk = blockIdx.y;

    const int bb = W * 32 + n;
    half8 af = make_afrag32(f4, bb, kh);

    // combine pass-1 partials for this lane's b-row (ascending chunks, first-max)
    float bvv = -INFINITY; int zi = 0;
#pragma unroll
    for (int cc = 0; cc < NCH; ++cc) {
        float v = P1v[(size_t)cc * NB + bb];
        int   i = P1i[(size_t)cc * NB + bb];
        if (v > bvv || (v == bvv && i < zi)) { bvv = v; zi = i; }
    }
    half8 df = {0, 0, 0, 0, 0, 0, 0, 0};
    if (kh == 1) {                           // z at k=9,10,11 -> j=1..3
        df[1] = (_Float16)gv[3 * zi + 0];
        df[2] = (_Float16)gv[3 * zi + 1];
        df[3] = (_Float16)gv[3 * zi + 2];
    }

    float bv[16]; int bidx[16];
#pragma unroll
    for (int r = 0; r < 16; ++r) { bv[r] = -INFINITY; bidx[r] = 0; }

    const int t0 = (NGT * chunk) / NCH;
    const int t1 = (NGT * (chunk + 1)) / NCH;
    const half8* bp = y4p + (size_t)(t0 * 32 + n) * 2 + kh;
    int gcur = t0 * 32 + n;
    const floatx16 zero16 = {0.f,0.f,0.f,0.f, 0.f,0.f,0.f,0.f, 0.f,0.f,0.f,0.f, 0.f,0.f,0.f,0.f};

    half8 bf = *bp;
    bp += 64;
#pragma unroll 2
    for (int t = t0; t < t1 - 1; ++t) {
        half8 bfn = *bp;
        bp += 64;
        floatx16 cs = __builtin_amdgcn_mfma_f32_32x32x16_f16(af, bf, zero16, 0, 0, 0);
        floatx16 cd = __builtin_amdgcn_mfma_f32_32x32x16_f16(df, bf, zero16, 0, 0, 0);
#pragma unroll
        for (int r = 0; r < 16; ++r) {
            float sm = (fabsf(cd[r]) < 0.2f) ? cs[r] : -INFINITY;  // NaN pad -> -INF
            bool gt = sm > bv[r];
            bv[r]   = gt ? sm : bv[r];
            bidx[r] = gt ? gcur : bidx[r];
        }
        gcur += 32;
        bf = bfn;
    }
    {
        floatx16 cs = __builtin_amdgcn_mfma_f32_32x32x16_f16(af, bf, zero16, 0, 0, 0);
        floatx16 cd = __builtin_amdgcn_mfma_f32_32x32x16_f16(df, bf, zero16, 0, 0, 0);
#pragma unroll
        for (int r = 0; r < 16; ++r) {
            float sm = (fabsf(cd[r]) < 0.2f) ? cs[r] : -INFINITY;
            bool gt = sm > bv[r];
            bv[r]   = gt ? sm : bv[r];
            bidx[r] = gt ? gcur : bidx[r];
        }
    }
#pragma unroll
    for (int r = 0; r < 16; ++r) {
        float v = bv[r];
        int   ii = bidx[r];
#pragma unroll
        for (int s = 1; s < 32; s <<= 1) {
            float ov = __shfl_xor(v, s);
            int   oi = __shfl_xor(ii, s);
            if (ov > v || (ov == v && oi < ii)) { v = ov; ii = oi; }
        }
        if (n == 0) {
            int b = W * 32 + (r & 3) + 8 * (r >> 2) + 4 * kh;
            P2v[(size_t)chunk * NB + b] = v;
            P2i[(size_t)chunk * NB + b] = ii;
        }
    }
}

// ---------------- Kernel 4: finalize — combine both passes, frame, quaternion, boundary map ----------------
__global__ __launch_bounds__(256) void k_final(const float* __restrict__ f0,
                                               const float* __restrict__ gv,
                                               const float* __restrict__ P1v,
                                               const int* __restrict__ P1i,
                                               const float* __restrict__ P2v,
                                               const int* __restrict__ P2i,
                                               float* __restrict__ out) {
    int b = blockIdx.x * 256 + threadIdx.x;
    float bz = -INFINITY; int zi = 0;
#pragma unroll
    for (int cc = 0; cc < NCH; ++cc) {
        float v = P1v[(size_t)cc * NB + b];
        int   i = P1i[(size_t)cc * NB + b];
        if (v > bz || (v == bz && i < zi)) { bz = v; zi = i; }
    }
    float bx = -INFINITY; int xi = 0;
#pragma unroll
    for (int cc = 0; cc < NCH; ++cc) {
        float v = P2v[(size_t)cc * NB + b];
        int   i = P2i[(size_t)cc * NB + b];
        if (v > bx || (v == bx && i < xi)) { bx = v; xi = i; }
    }
    float zr0 = gv[3 * zi], zr1 = gv[3 * zi + 1], zr2 = gv[3 * zi + 2];
    float xr0 = gv[3 * xi], xr1 = gv[3 * xi + 1], xr2 = gv[3 * xi + 2];
    float zn = sqrtf(zr0 * zr0 + zr1 * zr1 + zr2 * zr2);
    float zd = fmaxf(zn, 1e-12f);
    float z0 = zr0 / zd, z1 = zr1 / zd, z2 = zr2 / zd;
    float pr = xr0 * z0 + xr1 * z1 + xr2 * z2;
    float ux = xr0 - pr * z0, uy = xr1 - pr * z1, uz = xr2 - pr * z2;
    float xn = sqrtf(ux * ux + uy * uy + uz * uz);
    float xd = fmaxf(xn, 1e-12f);
    float x0 = ux / xd, x1 = uy / xd, x2 = uz / xd;
    float y0 = z1 * x2 - z2 * x1;
    float y1 = z2 * x0 - z0 * x2;
    float y2 = z0 * x1 - z1 * x0;
    float m00 = x0, m01 = y0, m02 = z0;
    float m10 = x1, m11 = y1, m12 = z1;
    float m20 = x2, m21 = y2, m22 = z2;
    float q0 = sqrtf(fmaxf(1.0f + m00 + m11 + m22, 0.0f));
    float q1 = sqrtf(fmaxf(1.0f + m00 - m11 - m22, 0.0f));
    float q2 = sqrtf(fmaxf(1.0f - m00 + m11 - m22, 0.0f));
    float q3 = sqrtf(fmaxf(1.0f - m00 - m11 + m22, 0.0f));
    int bq = 0; float qb = q0;
    if (q1 > qb) { qb = q1; bq = 1; }
    if (q2 > qb) { qb = q2; bq = 2; }
    if (q3 > qb) { qb = q3; bq = 3; }
    float dd = 2.0f * fmaxf(qb, 0.1f);
    float wq, qx, qy, qz;
    if (bq == 0)      { wq = q0 * q0;  qx = m21 - m12; qy = m02 - m20; qz = m10 - m01; }
    else if (bq == 1) { wq = m21 - m12; qx = q1 * q1;  qy = m10 + m01; qz = m02 + m20; }
    else if (bq == 2) { wq = m02 - m20; qx = m10 + m01; qy = q2 * q2;  qz = m12 + m21; }
    else              { wq = m10 - m01; qx = m20 + m02; qy = m21 + m12; qz = q3 * q3; }
    out[b * 4 + 0] = wq / dd;
    out[b * 4 + 1] = qx / dd;
    out[b * 4 + 2] = qy / dd;
    out[b * 4 + 3] = qz / dd;
    out[4 * NB + b] = f0[b] * (float)(180.0 / M_PI);
}

extern "C" void kernel_launch(void* const* d_in, const int* in_sizes, int n_in,
                              void* d_out, int out_size, void* d_ws, size_t ws_size,
                              hipStream_t stream) {
    const float* f0 = (const float*)d_in[0];   // [16384, 1]
    const float* f4 = (const float*)d_in[2];   // [16384, 9]
    const float* gv = (const float*)d_in[4];   // [10000, 3]
    float* out = (float*)d_out;
    (void)in_sizes; (void)n_in; (void)out_size; (void)ws_size;

    // ws layout (bytes): y4pack f16[NGPAD*16] = 320512 (slot 327680) |
    //   P1v f32[NCH*NB] 524288 | P1i 524288 | P2v 524288 | P2i 524288   (~2.42 MB)
    char* W = (char*)d_ws;
    half8* y4p = (half8*)W;
    float* P1v = (float*)(W + 327680);
    int*   P1i = (int*)(W + 327680 + 524288);
    float* P2v = (float*)(W + 327680 + 2 * 524288);
    int*   P2i = (int*)(W + 327680 + 3 * 524288);

    k_pack<<<(NGPAD + 255) / 256, 256, 0, stream>>>(gv, y4p);
    // 512 b-tiles / (4 waves/block) = 128 blocks in x; 8 chunks in y = 1024 blocks (4/CU)
    dim3 grid2(128, NCH);
    k_pass1<<<grid2, 256, 0, stream>>>(f4, y4p, P1v, P1i);
    k_pass2<<<grid2, 256, 0, stream>>>(f4, y4p, gv, P1v, P1i, P2v, P2i);
    k_final<<<NB / 256, 256, 0, stream>>>(f0, gv, P1v, P1i, P2v, P2i, out);
}